// Round 1
// baseline (429.313 us; speedup 1.0000x reference)
//
#include <hip/hip_runtime.h>

// Problem constants (fixed by reference setup_inputs)
constexpr int BN    = 262144;   // batch
constexpr int DIN   = 100;      // input dim
constexpr int DH    = 200;      // hidden dim
constexpr int DZ    = 20;       // latent
constexpr int KCB   = 512;      // codebook entries
constexpr int BLOCK = 256;
constexpr int NBLK  = BN / BLOCK;  // 1024

// ---------------------------------------------------------------------------
// Kernel 0: codebook squared norms -> ws[0..511]
// ---------------------------------------------------------------------------
__global__ void cbnorm_kernel(const float* __restrict__ cb, float* __restrict__ cbn2) {
    int k = blockIdx.x * blockDim.x + threadIdx.x;
    if (k < KCB) {
        const float* r = cb + k * DZ;
        float s = 0.f;
        #pragma unroll
        for (int d = 0; d < DZ; ++d) s = fmaf(r[d], r[d], s);
        cbn2[k] = s;
    }
}

// ---------------------------------------------------------------------------
// Main kernel: one thread per row.
//   h = elu(c@W1 + b1) computed in 4 chunks of 50 (registers, static idx)
//   z = h@W2 + b2 streamed (no h materialization)
//   VQ argmin over 512 codes using cbn2 - 2*z.cb
//   outputs mu, logvar, z_q(=quantized), z_e; per-block loss partial
// ---------------------------------------------------------------------------
__global__ __launch_bounds__(BLOCK) void vqvae_main(
    const float* __restrict__ c,
    const float* __restrict__ W1, const float* __restrict__ b1,
    const float* __restrict__ W2, const float* __restrict__ b2,
    const float* __restrict__ cb,
    const float* __restrict__ Wmu, const float* __restrict__ bmu,
    const float* __restrict__ Wlv, const float* __restrict__ blv,
    const float* __restrict__ cbn2,
    float* __restrict__ out, float* __restrict__ partials)
{
    const int row = blockIdx.x * BLOCK + threadIdx.x;
    const float4* crow4 = reinterpret_cast<const float4*>(c + (size_t)row * DIN);

    float z[DZ];
    #pragma unroll
    for (int k = 0; k < DZ; ++k) z[k] = b2[k];

    // ---- encoder: 4 chunks of 50 hidden units ----
    for (int jc = 0; jc < 4; ++jc) {          // dynamic: keeps code size down
        float hc[50];
        const float* b1p = b1 + jc * 50;
        #pragma unroll
        for (int j = 0; j < 50; ++j) hc[j] = b1p[j];

        const float* w1base = W1 + jc * 50;
        for (int ii = 0; ii < DIN / 4; ++ii) { // 25 iterations, dynamic
            float4 cv = crow4[ii];
            const float* w1p = w1base + (size_t)(ii * 4) * DH;
            #pragma unroll
            for (int j = 0; j < 50; ++j) {
                float a = hc[j];
                a = fmaf(cv.x, w1p[j],          a);
                a = fmaf(cv.y, w1p[DH + j],     a);
                a = fmaf(cv.z, w1p[2 * DH + j], a);
                a = fmaf(cv.w, w1p[3 * DH + j], a);
                hc[j] = a;
            }
        }

        // ELU + accumulate into z (W2 rows are contiguous, wave-uniform)
        const float* w2base = W2 + jc * 50 * DZ;
        #pragma unroll
        for (int j = 0; j < 50; ++j) {
            float hj = hc[j];
            hj = hj > 0.f ? hj : (__expf(hj) - 1.f);
            const float* w2p = w2base + j * DZ;
            #pragma unroll
            for (int k = 0; k < DZ; ++k) z[k] = fmaf(hj, w2p[k], z[k]);
        }
    }

    // ---- vector quantization: argmin_k cbn2[k] - 2*z.cb_k ----
    int best = 0;
    float bestd = 3.4e38f;
    for (int k = 0; k < KCB; ++k) {
        const float* cbr = cb + k * DZ;
        float dot = 0.f;
        #pragma unroll
        for (int d = 0; d < DZ; ++d) dot = fmaf(z[d], cbr[d], dot);
        float score = fmaf(-2.f, dot, cbn2[k]);
        if (score < bestd) { bestd = score; best = k; }  // strict <: first-min wins
    }

    // gather quantized row (per-lane, 16B-aligned: 80B stride)
    float q[DZ];
    const float4* qr4 = reinterpret_cast<const float4*>(cb + best * DZ);
    #pragma unroll
    for (int d4 = 0; d4 < DZ / 4; ++d4) {
        float4 v = qr4[d4];
        q[4 * d4 + 0] = v.x; q[4 * d4 + 1] = v.y;
        q[4 * d4 + 2] = v.z; q[4 * d4 + 3] = v.w;
    }

    // ---- loss partial: sum (q - z)^2 ----
    float lsum = 0.f;
    #pragma unroll
    for (int d = 0; d < DZ; ++d) { float df = q[d] - z[d]; lsum = fmaf(df, df, lsum); }

    // ---- mu / logvar projections ----
    float mu[DZ], lv[DZ];
    #pragma unroll
    for (int k = 0; k < DZ; ++k) { mu[k] = bmu[k]; lv[k] = blv[k]; }
    #pragma unroll
    for (int d = 0; d < DZ; ++d) {
        const float* wmr = Wmu + d * DZ;
        const float* wlr = Wlv + d * DZ;
        float zd = z[d];
        #pragma unroll
        for (int k = 0; k < DZ; ++k) {
            mu[k] = fmaf(zd, wmr[k], mu[k]);
            lv[k] = fmaf(zd, wlr[k], lv[k]);
        }
    }

    // ---- stores (float4, all 16B aligned: row*80B) ----
    const size_t ro = (size_t)row * DZ;
    const size_t SEC = (size_t)BN * DZ;
    float* o_mu = out + ro;
    float* o_lv = out + SEC + ro;
    float* o_zq = out + 2 * SEC + ro;
    float* o_ze = out + 3 * SEC + ro;
    #pragma unroll
    for (int d = 0; d < DZ; d += 4) {
        *reinterpret_cast<float4*>(o_mu + d) = make_float4(mu[d], mu[d+1], mu[d+2], mu[d+3]);
        *reinterpret_cast<float4*>(o_lv + d) = make_float4(lv[d], lv[d+1], lv[d+2], lv[d+3]);
        *reinterpret_cast<float4*>(o_zq + d) = make_float4(q[d],  q[d+1],  q[d+2],  q[d+3]);
        *reinterpret_cast<float4*>(o_ze + d) = make_float4(z[d],  z[d+1],  z[d+2],  z[d+3]);
    }

    // ---- deterministic block reduction of loss partial ----
    #pragma unroll
    for (int off = 32; off > 0; off >>= 1) lsum += __shfl_down(lsum, off, 64);
    __shared__ float wsum[BLOCK / 64];
    const int lane = threadIdx.x & 63, wid = threadIdx.x >> 6;
    if (lane == 0) wsum[wid] = lsum;
    __syncthreads();
    if (threadIdx.x == 0)
        partials[blockIdx.x] = (wsum[0] + wsum[1]) + (wsum[2] + wsum[3]);
}

// ---------------------------------------------------------------------------
// Final reduction: 1024 partials -> two scalar losses (deterministic tree)
// ---------------------------------------------------------------------------
__global__ __launch_bounds__(256) void loss_reduce(const float* __restrict__ partials,
                                                   float* __restrict__ out_scalars) {
    int t = threadIdx.x;
    float s = (partials[t] + partials[t + 256]) + (partials[t + 512] + partials[t + 768]);
    #pragma unroll
    for (int off = 32; off > 0; off >>= 1) s += __shfl_down(s, off, 64);
    __shared__ float wsum[4];
    if ((t & 63) == 0) wsum[t >> 6] = s;
    __syncthreads();
    if (t == 0) {
        float total = (wsum[0] + wsum[1]) + (wsum[2] + wsum[3]);
        float ql = total / (float)(BN * DZ);
        out_scalars[0] = ql;          // quantization_loss
        out_scalars[1] = 0.25f * ql;  // commitment_loss (same squared diff)
    }
}

// ---------------------------------------------------------------------------
extern "C" void kernel_launch(void* const* d_in, const int* in_sizes, int n_in,
                              void* d_out, int out_size, void* d_ws, size_t ws_size,
                              hipStream_t stream) {
    const float* c   = (const float*)d_in[0];
    const float* W1  = (const float*)d_in[1];
    const float* b1  = (const float*)d_in[2];
    const float* W2  = (const float*)d_in[3];
    const float* b2  = (const float*)d_in[4];
    const float* cb  = (const float*)d_in[5];
    const float* Wmu = (const float*)d_in[6];
    const float* bmu = (const float*)d_in[7];
    const float* Wlv = (const float*)d_in[8];
    const float* blv = (const float*)d_in[9];
    float* out = (float*)d_out;

    float* wsf      = (float*)d_ws;
    float* cbn2     = wsf;          // 512 floats
    float* partials = wsf + 512;    // 1024 floats

    cbnorm_kernel<<<1, 512, 0, stream>>>(cb, cbn2);
    vqvae_main<<<NBLK, BLOCK, 0, stream>>>(c, W1, b1, W2, b2, cb,
                                           Wmu, bmu, Wlv, blv, cbn2,
                                           out, partials);
    loss_reduce<<<1, 256, 0, stream>>>(partials, out + 4ULL * BN * DZ);
}

// Round 2
// 306.803 us; speedup vs baseline: 1.3993x; 1.3993x over previous
//
#include <hip/hip_runtime.h>

// Problem constants (fixed by reference setup_inputs)
constexpr int BN    = 262144;   // batch
constexpr int DIN   = 100;      // input dim
constexpr int DH    = 200;      // hidden dim
constexpr int DZ    = 20;       // latent
constexpr int KCB   = 512;      // codebook entries

// encoder kernel geometry
constexpr int ROWS_A = 64;      // rows per block
constexpr int THR_A  = 256;     // 4 waves: wave w handles j-slice w
constexpr int JSL    = 50;      // hidden cols per wave (4*50 = 200)
constexpr int CPAD   = 101;     // odd pad: 2-way LDS access = free
constexpr int ZPAD   = 21;

// head kernel geometry
constexpr int THR_B  = 256;
constexpr int NBLK_B = BN / THR_B;   // 1024

// ---------------------------------------------------------------------------
// Kernel 0: codebook squared norms -> ws[0..511]
// ---------------------------------------------------------------------------
__global__ void cbnorm_kernel(const float* __restrict__ cb, float* __restrict__ cbn2) {
    int k = blockIdx.x * blockDim.x + threadIdx.x;
    if (k < KCB) {
        const float* r = cb + k * DZ;
        float s = 0.f;
        #pragma unroll
        for (int d = 0; d < DZ; ++d) s = fmaf(r[d], r[d], s);
        cbn2[k] = s;
    }
}

// ---------------------------------------------------------------------------
// Kernel A: encoder. 64 rows/block; c staged coalesced into LDS once.
// Wave w computes h[j] for j in [w*50, w*50+50) for all 64 rows (lane = row).
// Weight addresses wave-uniform via readfirstlane -> s_load scalarization.
// z partials combined across waves through LDS; z_e stored to out.
// ---------------------------------------------------------------------------
__global__ __launch_bounds__(THR_A, 4) void encoder_kernel(
    const float* __restrict__ c,
    const float* __restrict__ W1, const float* __restrict__ b1,
    const float* __restrict__ W2, const float* __restrict__ b2,
    float* __restrict__ z_out)
{
    __shared__ float lds[ROWS_A * CPAD];   // 6464 floats; z-partials alias it later
    const int tid = threadIdx.x;
    const int L   = tid & 63;                                  // row within block
    const int wu  = __builtin_amdgcn_readfirstlane(tid >> 6);  // wave id, SGPR-uniform
    const int row0 = blockIdx.x * ROWS_A;

    // ---- stage c rows [row0, row0+64): 6400 contiguous floats, coalesced ----
    const float* cblk = c + (size_t)row0 * DIN;
    #pragma unroll
    for (int i = 0; i < 25; ++i) {
        int flat = i * THR_A + tid;            // 0..6399
        float v = cblk[flat];
        int r = flat / DIN, k = flat - r * DIN;
        lds[r * CPAD + k] = v;
    }
    __syncthreads();

    // ---- h slice: row L, cols [wu*50, wu*50+50) ----
    float h[JSL];
    const float* b1s = b1 + wu * JSL;
    #pragma unroll
    for (int j = 0; j < JSL; ++j) h[j] = b1s[j];

    const float* w1s  = W1 + wu * JSL;
    const float* crow = lds + L * CPAD;
    #pragma unroll 4
    for (int k = 0; k < DIN; ++k) {
        float cv = crow[k];                    // ds_read, 2-way banks (101 odd)
        const float* wr = w1s + (size_t)k * DH;  // wave-uniform -> s_load
        #pragma unroll
        for (int j = 0; j < JSL; ++j) h[j] = fmaf(cv, wr[j], h[j]);
    }

    // ---- ELU + W2 partial (z contribution of this j-slice) ----
    float zp[DZ];
    #pragma unroll
    for (int d = 0; d < DZ; ++d) zp[d] = 0.f;
    const float* w2s = W2 + (size_t)wu * JSL * DZ;
    #pragma unroll
    for (int j = 0; j < JSL; ++j) {
        float hj = h[j];
        hj = hj > 0.f ? hj : (__expf(hj) - 1.f);
        const float* wr = w2s + j * DZ;        // wave-uniform -> s_load
        #pragma unroll
        for (int d = 0; d < DZ; ++d) zp[d] = fmaf(hj, wr[d], zp[d]);
    }

    // ---- cross-wave combine via LDS (aliases the c tile; barrier-separated) ----
    __syncthreads();                           // all waves done reading c
    float* zb = lds;                           // [4][ROWS_A][ZPAD]
    #pragma unroll
    for (int d = 0; d < DZ; ++d)
        zb[(wu * ROWS_A + L) * ZPAD + d] = zp[d];
    __syncthreads();

    // thread (wu, L): finalize dims [wu*5, wu*5+5) of row L, store z_e
    const int dgo = wu * 5;
    float* zo = z_out + (size_t)(row0 + L) * DZ + dgo;
    #pragma unroll
    for (int i = 0; i < 5; ++i) {
        int d = dgo + i;
        float s = ((zb[(0 * ROWS_A + L) * ZPAD + d] + zb[(1 * ROWS_A + L) * ZPAD + d])
                 + (zb[(2 * ROWS_A + L) * ZPAD + d] + zb[(3 * ROWS_A + L) * ZPAD + d]))
                 + b2[d];
        zo[i] = s;
    }
}

// ---------------------------------------------------------------------------
// Kernel B: VQ + heads, thread-per-row (math identical to round-1 passing kernel).
// Reads z_e back from out (80 B rows -> contiguous 5 KB wave footprint).
// ---------------------------------------------------------------------------
__global__ __launch_bounds__(THR_B, 4) void vq_head_kernel(
    const float* __restrict__ z_in, const float* __restrict__ cb,
    const float* __restrict__ cbn2,
    const float* __restrict__ Wmu, const float* __restrict__ bmu,
    const float* __restrict__ Wlv, const float* __restrict__ blv,
    float* __restrict__ out, float* __restrict__ partials)
{
    const int row = blockIdx.x * THR_B + threadIdx.x;

    float z[DZ];
    const float4* z4 = reinterpret_cast<const float4*>(z_in + (size_t)row * DZ);
    #pragma unroll
    for (int i = 0; i < DZ / 4; ++i) {
        float4 v = z4[i];
        z[4*i] = v.x; z[4*i+1] = v.y; z[4*i+2] = v.z; z[4*i+3] = v.w;
    }

    // ---- VQ: argmin_k cbn2[k] - 2*z.cb_k  (strict <: first-min wins) ----
    int best = 0;
    float bestd = 3.4e38f;
    for (int k = 0; k < KCB; ++k) {
        const float* cbr = cb + k * DZ;        // wave-uniform -> s_load
        float dot = 0.f;
        #pragma unroll
        for (int d = 0; d < DZ; ++d) dot = fmaf(z[d], cbr[d], dot);
        float score = fmaf(-2.f, dot, cbn2[k]);
        if (score < bestd) { bestd = score; best = k; }
    }

    // gather quantized row
    float q[DZ];
    const float4* qr4 = reinterpret_cast<const float4*>(cb + best * DZ);
    #pragma unroll
    for (int d4 = 0; d4 < DZ / 4; ++d4) {
        float4 v = qr4[d4];
        q[4*d4+0] = v.x; q[4*d4+1] = v.y; q[4*d4+2] = v.z; q[4*d4+3] = v.w;
    }

    // loss partial
    float lsum = 0.f;
    #pragma unroll
    for (int d = 0; d < DZ; ++d) { float df = q[d] - z[d]; lsum = fmaf(df, df, lsum); }

    // mu / logvar
    float mu[DZ], lv[DZ];
    #pragma unroll
    for (int k = 0; k < DZ; ++k) { mu[k] = bmu[k]; lv[k] = blv[k]; }
    #pragma unroll
    for (int d = 0; d < DZ; ++d) {
        const float* wmr = Wmu + d * DZ;
        const float* wlr = Wlv + d * DZ;
        float zd = z[d];
        #pragma unroll
        for (int k = 0; k < DZ; ++k) {
            mu[k] = fmaf(zd, wmr[k], mu[k]);
            lv[k] = fmaf(zd, wlr[k], lv[k]);
        }
    }

    // stores (float4; row stride 80 B keeps 16-B alignment)
    const size_t ro  = (size_t)row * DZ;
    const size_t SEC = (size_t)BN * DZ;
    float* o_mu = out + ro;
    float* o_lv = out + SEC + ro;
    float* o_zq = out + 2 * SEC + ro;
    #pragma unroll
    for (int d = 0; d < DZ; d += 4) {
        *reinterpret_cast<float4*>(o_mu + d) = make_float4(mu[d], mu[d+1], mu[d+2], mu[d+3]);
        *reinterpret_cast<float4*>(o_lv + d) = make_float4(lv[d], lv[d+1], lv[d+2], lv[d+3]);
        *reinterpret_cast<float4*>(o_zq + d) = make_float4(q[d],  q[d+1],  q[d+2],  q[d+3]);
    }

    // deterministic block reduction of loss partial
    #pragma unroll
    for (int off = 32; off > 0; off >>= 1) lsum += __shfl_down(lsum, off, 64);
    __shared__ float wsum[THR_B / 64];
    const int lane = threadIdx.x & 63, wid = threadIdx.x >> 6;
    if (lane == 0) wsum[wid] = lsum;
    __syncthreads();
    if (threadIdx.x == 0)
        partials[blockIdx.x] = (wsum[0] + wsum[1]) + (wsum[2] + wsum[3]);
}

// ---------------------------------------------------------------------------
// Final reduction: 1024 partials -> two scalar losses (deterministic tree)
// ---------------------------------------------------------------------------
__global__ __launch_bounds__(256) void loss_reduce(const float* __restrict__ partials,
                                                   float* __restrict__ out_scalars) {
    int t = threadIdx.x;
    float s = (partials[t] + partials[t + 256]) + (partials[t + 512] + partials[t + 768]);
    #pragma unroll
    for (int off = 32; off > 0; off >>= 1) s += __shfl_down(s, off, 64);
    __shared__ float wsum[4];
    if ((t & 63) == 0) wsum[t >> 6] = s;
    __syncthreads();
    if (t == 0) {
        float total = (wsum[0] + wsum[1]) + (wsum[2] + wsum[3]);
        float ql = total / (float)(BN * DZ);
        out_scalars[0] = ql;          // quantization_loss
        out_scalars[1] = 0.25f * ql;  // commitment_loss
    }
}

// ---------------------------------------------------------------------------
extern "C" void kernel_launch(void* const* d_in, const int* in_sizes, int n_in,
                              void* d_out, int out_size, void* d_ws, size_t ws_size,
                              hipStream_t stream) {
    const float* c   = (const float*)d_in[0];
    const float* W1  = (const float*)d_in[1];
    const float* b1  = (const float*)d_in[2];
    const float* W2  = (const float*)d_in[3];
    const float* b2  = (const float*)d_in[4];
    const float* cb  = (const float*)d_in[5];
    const float* Wmu = (const float*)d_in[6];
    const float* bmu = (const float*)d_in[7];
    const float* Wlv = (const float*)d_in[8];
    const float* blv = (const float*)d_in[9];
    float* out = (float*)d_out;

    float* wsf      = (float*)d_ws;
    float* cbn2     = wsf;          // 512 floats
    float* partials = wsf + 512;    // 1024 floats

    const size_t SEC = (size_t)BN * DZ;
    float* z_e = out + 3 * SEC;     // z_e section: written by A, read by B

    cbnorm_kernel<<<1, 512, 0, stream>>>(cb, cbn2);
    encoder_kernel<<<BN / ROWS_A, THR_A, 0, stream>>>(c, W1, b1, W2, b2, z_e);
    vq_head_kernel<<<NBLK_B, THR_B, 0, stream>>>(z_e, cb, cbn2,
                                                 Wmu, bmu, Wlv, blv,
                                                 out, partials);
    loss_reduce<<<1, 256, 0, stream>>>(partials, out + 4 * SEC);
}

// Round 3
// 111.099 us; speedup vs baseline: 3.8643x; 2.7615x over previous
//
#include <hip/hip_runtime.h>

typedef __bf16 bf16x8 __attribute__((ext_vector_type(8)));
typedef float  f32x4  __attribute__((ext_vector_type(4)));

constexpr int BN  = 262144;
constexpr int DIN = 100;
constexpr int DH  = 200;
constexpr int DZ  = 20;
constexpr int KCB = 512;

// ws byte offsets (all 16B-aligned)
constexpr size_t WS_W1F  = 0;        // [16 nt][4 kk][512] bf16 = 65536 B
constexpr size_t WS_W2F  = 65536;    // [2 zt][8 kk][512] bf16 = 16384 B
constexpr size_t WS_CBF  = 81920;    // [32 ct][512] bf16 = 32768 B
constexpr size_t WS_WMUF = 114688;   // [2 zt][512] bf16 = 2048 B
constexpr size_t WS_WLVF = 116736;   // 2048 B
constexpr size_t WS_B1P  = 118784;   // 256 f32
constexpr size_t WS_B2P  = 119808;   // 32 f32
constexpr size_t WS_BMUP = 119936;   // 32 f32
constexpr size_t WS_BLVP = 120064;   // 32 f32
constexpr size_t WS_CBN2 = 120192;   // 512 f32
constexpr size_t WS_PART = 122240;   // 2048 f32

// prep element counts
constexpr int PN_W1 = 32768, PN_W2 = 8192, PN_CB = 16384, PN_WMU = 1024, PN_WLV = 1024;
constexpr int PN_TOT = PN_W1 + PN_W2 + PN_CB + PN_WMU + PN_WLV + 256 + 32 + 32 + 32 + 512;

// ---------------------------------------------------------------------------
// Prep: pack weights into MFMA B-fragment order (lane l, elem j:
// B[k=(l>>4)*8+j][n=l&15]), pad biases, codebook norms.
// ---------------------------------------------------------------------------
__global__ __launch_bounds__(256) void prep_kernel(
    const float* __restrict__ W1, const float* __restrict__ b1,
    const float* __restrict__ W2, const float* __restrict__ b2,
    const float* __restrict__ cb,
    const float* __restrict__ Wmu, const float* __restrict__ bmu,
    const float* __restrict__ Wlv, const float* __restrict__ blv,
    unsigned char* __restrict__ ws)
{
    int e = blockIdx.x * 256 + threadIdx.x;
    if (e >= PN_TOT) return;
    __bf16* w1f  = (__bf16*)(ws + WS_W1F);
    __bf16* w2f  = (__bf16*)(ws + WS_W2F);
    __bf16* cbf  = (__bf16*)(ws + WS_CBF);
    __bf16* wmuf = (__bf16*)(ws + WS_WMUF);
    __bf16* wlvf = (__bf16*)(ws + WS_WLVF);
    float* b1p  = (float*)(ws + WS_B1P);
    float* b2p  = (float*)(ws + WS_B2P);
    float* bmup = (float*)(ws + WS_BMUP);
    float* blvp = (float*)(ws + WS_BLVP);
    float* cbn2 = (float*)(ws + WS_CBN2);

    if (e < PN_W1) {  // [nt][kk][lane][j]
        int j = e & 7, lane = (e >> 3) & 63, kk = (e >> 9) & 3, nt = e >> 11;
        int n = nt * 16 + (lane & 15);
        int k = kk * 32 + ((lane >> 4) << 3) + j;
        w1f[e] = (__bf16)((n < DH && k < DIN) ? W1[k * DH + n] : 0.f);
        return;
    }
    e -= PN_W1;
    if (e < PN_W2) {  // [zt][kk][lane][j], K=256 over h-dim
        int j = e & 7, lane = (e >> 3) & 63, kk = (e >> 9) & 7, zt = e >> 12;
        int n = zt * 16 + (lane & 15);
        int k = kk * 32 + ((lane >> 4) << 3) + j;
        w2f[e - 0] = (__bf16)((n < DZ && k < DH) ? W2[k * DZ + n] : 0.f);
        return;
    }
    e -= PN_W2;
    if (e < PN_CB) {  // [ct][lane][j]: value = -2*cb[code][d]
        int j = e & 7, lane = (e >> 3) & 63, ct = e >> 9;
        int code = ct * 16 + (lane & 15);
        int d = ((lane >> 4) << 3) + j;
        cbf[e] = (__bf16)((d < DZ) ? -2.f * cb[code * DZ + d] : 0.f);
        return;
    }
    e -= PN_CB;
    if (e < PN_WMU) {
        int j = e & 7, lane = (e >> 3) & 63, zt = e >> 9;
        int n = zt * 16 + (lane & 15);
        int k = ((lane >> 4) << 3) + j;
        wmuf[e] = (__bf16)((n < DZ && k < DZ) ? Wmu[k * DZ + n] : 0.f);
        return;
    }
    e -= PN_WMU;
    if (e < PN_WLV) {
        int j = e & 7, lane = (e >> 3) & 63, zt = e >> 9;
        int n = zt * 16 + (lane & 15);
        int k = ((lane >> 4) << 3) + j;
        wlvf[e] = (__bf16)((n < DZ && k < DZ) ? Wlv[k * DZ + n] : 0.f);
        return;
    }
    e -= PN_WLV;
    if (e < 256) { b1p[e] = (e < DH) ? b1[e] : 0.f; return; }
    e -= 256;
    if (e < 32) { b2p[e] = (e < DZ) ? b2[e] : 0.f; return; }
    e -= 32;
    if (e < 32) { bmup[e] = (e < DZ) ? bmu[e] : 0.f; return; }
    e -= 32;
    if (e < 32) { blvp[e] = (e < DZ) ? blv[e] : 0.f; return; }
    e -= 32;
    // cbn2 fp32
    float s = 0.f;
    const float* r = cb + e * DZ;
    #pragma unroll
    for (int d = 0; d < DZ; ++d) s = fmaf(r[d], r[d], s);
    cbn2[e] = s;
}

// ---------------------------------------------------------------------------
// Fused main: 128 rows/block, 4 waves, 32 rows/wave (2 M-tiles).
// GEMM1 (c@W1+b1, ELU) -> h LDS (bf16, swizzled) -> GEMM2 (z) ->
// VQ argmin via MFMA -> gather/losses -> heads (mu, logvar).
// ---------------------------------------------------------------------------
__global__ __launch_bounds__(256) void fused_main(
    const float* __restrict__ c, const float* __restrict__ cb,
    const unsigned char* __restrict__ ws, float* __restrict__ out,
    float* __restrict__ partials)
{
    __shared__ __align__(16) unsigned char lds_raw[43024];
    unsigned char* hT = lds_raw;            // [128 rows][256 B] (128 bf16 cols/half)
    unsigned char* zT = lds_raw + 32768;    // [128 rows][64 B]  (32 bf16 cols)
    float* cb2 = (float*)(lds_raw + 40960); // 512 f32
    float* red = (float*)(lds_raw + 43008); // 4 f32

    const __bf16* w1f  = (const __bf16*)(ws + WS_W1F);
    const __bf16* w2f  = (const __bf16*)(ws + WS_W2F);
    const __bf16* cbf  = (const __bf16*)(ws + WS_CBF);
    const __bf16* wmuf = (const __bf16*)(ws + WS_WMUF);
    const __bf16* wlvf = (const __bf16*)(ws + WS_WLVF);
    const float* b1p  = (const float*)(ws + WS_B1P);
    const float* b2p  = (const float*)(ws + WS_B2P);
    const float* bmup = (const float*)(ws + WS_BMUP);
    const float* blvp = (const float*)(ws + WS_BLVP);
    const float* cbn2g = (const float*)(ws + WS_CBN2);

    const int tid = threadIdx.x;
    const int l   = tid & 63;
    const int wid = __builtin_amdgcn_readfirstlane(tid >> 6);
    const int g   = l >> 4;      // lane group 0..3
    const int li  = l & 15;
    const int rowB = blockIdx.x * 128;          // block row base
    const int row0 = rowB + wid * 32;           // wave row base

    // stage cbn2 into LDS (read in VQ phase)
    cb2[tid]       = cbn2g[tid];
    cb2[tid + 256] = cbn2g[tid + 256];
    __syncthreads();

    // ---- A-fragments of c (K=128 padded), held in regs for whole GEMM1 ----
    bf16x8 af[2][4];
    #pragma unroll
    for (int mt = 0; mt < 2; ++mt) {
        const float* crow = c + (size_t)(row0 + mt * 16 + li) * DIN;
        #pragma unroll
        for (int kk = 0; kk < 4; ++kk) {
            int kb = kk * 32 + g * 8;
            float4 v0 = make_float4(0.f, 0.f, 0.f, 0.f);
            float4 v1 = make_float4(0.f, 0.f, 0.f, 0.f);
            if (kb <= 96)     v0 = *(const float4*)(crow + kb);
            if (kb + 4 <= 96) v1 = *(const float4*)(crow + kb + 4);
            bf16x8 a;
            a[0] = (__bf16)v0.x; a[1] = (__bf16)v0.y; a[2] = (__bf16)v0.z; a[3] = (__bf16)v0.w;
            a[4] = (__bf16)v1.x; a[5] = (__bf16)v1.y; a[6] = (__bf16)v1.z; a[7] = (__bf16)v1.w;
            af[mt][kk] = a;
        }
    }

    // GEMM2 accumulators (init with b2 bias; col li / 16+li)
    f32x4 z00, z01, z10, z11;
    {
        float bz0 = b2p[li], bz1 = b2p[16 + li];
        z00 = f32x4{bz0, bz0, bz0, bz0}; z01 = f32x4{bz1, bz1, bz1, bz1};
        z10 = z00; z11 = z01;
    }

    // ---- two half-tiles of the hidden dim (cols 0..127, 128..255) ----
    #pragma unroll
    for (int hf = 0; hf < 2; ++hf) {
        // GEMM1 for 8 n-tiles of this half
        #pragma unroll
        for (int t = 0; t < 8; ++t) {
            const int nt = hf * 8 + t;
            float bias = b1p[nt * 16 + li];
            f32x4 acc0 = f32x4{bias, bias, bias, bias};
            f32x4 acc1 = acc0;
            #pragma unroll
            for (int kk = 0; kk < 4; ++kk) {
                bf16x8 bw = *(const bf16x8*)(w1f + ((nt * 4 + kk) * 512 + l * 8));
                acc0 = __builtin_amdgcn_mfma_f32_16x16x32_bf16(af[0][kk], bw, acc0, 0, 0, 0);
                acc1 = __builtin_amdgcn_mfma_f32_16x16x32_bf16(af[1][kk], bw, acc1, 0, 0, 0);
            }
            // ELU + bf16 -> h LDS (swizzled)
            #pragma unroll
            for (int mt = 0; mt < 2; ++mt) {
                f32x4 a = mt ? acc1 : acc0;
                #pragma unroll
                for (int r = 0; r < 4; ++r) {
                    float h = a[r];
                    h = h > 0.f ? h : (__expf(h) - 1.f);
                    int lrow = wid * 32 + mt * 16 + g * 4 + r;
                    int cbyte = ((t * 16 + li) << 1) ^ ((lrow & 7) << 4);
                    *(__bf16*)(hT + lrow * 256 + cbyte) = (__bf16)h;
                }
            }
        }
        // GEMM2 partial: K-slice [hf*128, hf*128+128)
        #pragma unroll
        for (int kk = 0; kk < 4; ++kk) {
            const int kk2 = hf * 4 + kk;
            int lrow0 = wid * 32 + li;
            int lrow1 = lrow0 + 16;
            int cb0 = (kk * 64 + g * 16) ^ ((lrow0 & 7) << 4);
            int cb1 = (kk * 64 + g * 16) ^ ((lrow1 & 7) << 4);
            bf16x8 a20 = *(const bf16x8*)(hT + lrow0 * 256 + cb0);
            bf16x8 a21 = *(const bf16x8*)(hT + lrow1 * 256 + cb1);
            bf16x8 w20 = *(const bf16x8*)(w2f + ((0 * 8 + kk2) * 512 + l * 8));
            bf16x8 w21 = *(const bf16x8*)(w2f + ((1 * 8 + kk2) * 512 + l * 8));
            z00 = __builtin_amdgcn_mfma_f32_16x16x32_bf16(a20, w20, z00, 0, 0, 0);
            z01 = __builtin_amdgcn_mfma_f32_16x16x32_bf16(a20, w21, z01, 0, 0, 0);
            z10 = __builtin_amdgcn_mfma_f32_16x16x32_bf16(a21, w20, z10, 0, 0, 0);
            z11 = __builtin_amdgcn_mfma_f32_16x16x32_bf16(a21, w21, z11, 0, 0, 0);
        }
    }

    const size_t SEC = (size_t)BN * DZ;
    float* o_mu = out;
    float* o_lv = out + SEC;
    float* o_zq = out + 2 * SEC;
    float* o_ze = out + 3 * SEC;

    // ---- store z_e (fp32 accs) + write z tile to LDS (bf16, swizzled) ----
    #pragma unroll
    for (int mt = 0; mt < 2; ++mt) {
        f32x4 a0 = mt ? z10 : z00;
        f32x4 a1 = mt ? z11 : z01;
        #pragma unroll
        for (int r = 0; r < 4; ++r) {
            int lrow = wid * 32 + mt * 16 + g * 4 + r;
            int grow = rowB + lrow;
            o_ze[(size_t)grow * DZ + li] = a0[r];
            if (li < 4) o_ze[(size_t)grow * DZ + 16 + li] = a1[r];
            int swz = (lrow & 3) << 4;
            *(__bf16*)(zT + lrow * 64 + ((li << 1) ^ swz)) = (__bf16)a0[r];
            *(__bf16*)(zT + lrow * 64 + (((16 + li) << 1) ^ swz)) =
                (li < 4) ? (__bf16)a1[r] : (__bf16)0.f;
        }
    }

    // ---- VQ A-fragments (z rows, K=32) ----
    bf16x8 za0, za1;
    {
        int lrow0 = wid * 32 + li, lrow1 = lrow0 + 16;
        za0 = *(const bf16x8*)(zT + lrow0 * 64 + ((g * 16) ^ ((lrow0 & 3) << 4)));
        za1 = *(const bf16x8*)(zT + lrow1 * 64 + ((g * 16) ^ ((lrow1 & 3) << 4)));
    }

    // ---- VQ: 32 code-tiles, running argmin (strict <, ascending idx) ----
    float bs0[4], bs1[4]; int bi0[4], bi1[4];
    #pragma unroll
    for (int r = 0; r < 4; ++r) { bs0[r] = 3.4e38f; bs1[r] = 3.4e38f; bi0[r] = 0; bi1[r] = 0; }
    const f32x4 zero4 = f32x4{0.f, 0.f, 0.f, 0.f};
    #pragma unroll 4
    for (int ct = 0; ct < 32; ++ct) {
        bf16x8 cf = *(const bf16x8*)(cbf + (ct * 512 + l * 8));
        f32x4 s0 = __builtin_amdgcn_mfma_f32_16x16x32_bf16(za0, cf, zero4, 0, 0, 0);
        f32x4 s1 = __builtin_amdgcn_mfma_f32_16x16x32_bf16(za1, cf, zero4, 0, 0, 0);
        float c2 = cb2[ct * 16 + li];
        int idx = ct * 16 + li;
        #pragma unroll
        for (int r = 0; r < 4; ++r) {
            float sc0 = s0[r] + c2;
            if (sc0 < bs0[r]) { bs0[r] = sc0; bi0[r] = idx; }
            float sc1 = s1[r] + c2;
            if (sc1 < bs1[r]) { bs1[r] = sc1; bi1[r] = idx; }
        }
    }
    // reduce across the 16 lanes of each group (tie -> lower index)
    #pragma unroll
    for (int m = 1; m < 16; m <<= 1) {
        #pragma unroll
        for (int r = 0; r < 4; ++r) {
            float os = __shfl_xor(bs0[r], m, 64); int oi = __shfl_xor(bi0[r], m, 64);
            if (os < bs0[r] || (os == bs0[r] && oi < bi0[r])) { bs0[r] = os; bi0[r] = oi; }
            os = __shfl_xor(bs1[r], m, 64); oi = __shfl_xor(bi1[r], m, 64);
            if (os < bs1[r] || (os == bs1[r] && oi < bi1[r])) { bs1[r] = os; bi1[r] = oi; }
        }
    }

    // ---- gather quantized rows, store z_q, loss partial ----
    float lsum = 0.f;
    #pragma unroll
    for (int mt = 0; mt < 2; ++mt) {
        f32x4 a0 = mt ? z10 : z00;
        f32x4 a1 = mt ? z11 : z01;
        #pragma unroll
        for (int r = 0; r < 4; ++r) {
            int grow = rowB + wid * 32 + mt * 16 + g * 4 + r;
            int idx = mt ? bi1[r] : bi0[r];
            float qv = cb[idx * DZ + li];
            o_zq[(size_t)grow * DZ + li] = qv;
            float d0 = qv - a0[r];
            lsum = fmaf(d0, d0, lsum);
            if (li < 4) {
                float qv2 = cb[idx * DZ + 16 + li];
                o_zq[(size_t)grow * DZ + 16 + li] = qv2;
                float d1 = qv2 - a1[r];
                lsum = fmaf(d1, d1, lsum);
            }
        }
    }

    // ---- heads: mu, logvar (A = z frags, 8 MFMAs) ----
    {
        float bm0 = bmup[li], bm1 = bmup[16 + li];
        float bv0 = blvp[li], bv1 = blvp[16 + li];
        bf16x8 wm0 = *(const bf16x8*)(wmuf + (0 * 512 + l * 8));
        bf16x8 wm1 = *(const bf16x8*)(wmuf + (1 * 512 + l * 8));
        bf16x8 wl0 = *(const bf16x8*)(wlvf + (0 * 512 + l * 8));
        bf16x8 wl1 = *(const bf16x8*)(wlvf + (1 * 512 + l * 8));
        #pragma unroll
        for (int mt = 0; mt < 2; ++mt) {
            bf16x8 za = mt ? za1 : za0;
            f32x4 m0 = f32x4{bm0, bm0, bm0, bm0};
            f32x4 m1 = f32x4{bm1, bm1, bm1, bm1};
            f32x4 v0 = f32x4{bv0, bv0, bv0, bv0};
            f32x4 v1 = f32x4{bv1, bv1, bv1, bv1};
            m0 = __builtin_amdgcn_mfma_f32_16x16x32_bf16(za, wm0, m0, 0, 0, 0);
            m1 = __builtin_amdgcn_mfma_f32_16x16x32_bf16(za, wm1, m1, 0, 0, 0);
            v0 = __builtin_amdgcn_mfma_f32_16x16x32_bf16(za, wl0, v0, 0, 0, 0);
            v1 = __builtin_amdgcn_mfma_f32_16x16x32_bf16(za, wl1, v1, 0, 0, 0);
            #pragma unroll
            for (int r = 0; r < 4; ++r) {
                int grow = rowB + wid * 32 + mt * 16 + g * 4 + r;
                o_mu[(size_t)grow * DZ + li] = m0[r];
                o_lv[(size_t)grow * DZ + li] = v0[r];
                if (li < 4) {
                    o_mu[(size_t)grow * DZ + 16 + li] = m1[r];
                    o_lv[(size_t)grow * DZ + 16 + li] = v1[r];
                }
            }
        }
    }

    // ---- deterministic loss reduction ----
    #pragma unroll
    for (int off = 32; off > 0; off >>= 1) lsum += __shfl_down(lsum, off, 64);
    if (l == 0) red[wid] = lsum;
    __syncthreads();
    if (tid == 0)
        partials[blockIdx.x] = (red[0] + red[1]) + (red[2] + red[3]);
}

// ---------------------------------------------------------------------------
// Final reduction: 2048 partials -> two scalar losses (deterministic tree)
// ---------------------------------------------------------------------------
__global__ __launch_bounds__(256) void loss_reduce(const float* __restrict__ partials,
                                                   float* __restrict__ out_scalars) {
    int t = threadIdx.x;
    float s = 0.f;
    #pragma unroll
    for (int i = 0; i < 8; ++i) s += partials[t + 256 * i];
    #pragma unroll
    for (int off = 32; off > 0; off >>= 1) s += __shfl_down(s, off, 64);
    __shared__ float wsum[4];
    if ((t & 63) == 0) wsum[t >> 6] = s;
    __syncthreads();
    if (t == 0) {
        float total = (wsum[0] + wsum[1]) + (wsum[2] + wsum[3]);
        float ql = total / (float)((size_t)BN * DZ);
        out_scalars[0] = ql;          // quantization_loss
        out_scalars[1] = 0.25f * ql;  // commitment_loss
    }
}

// ---------------------------------------------------------------------------
extern "C" void kernel_launch(void* const* d_in, const int* in_sizes, int n_in,
                              void* d_out, int out_size, void* d_ws, size_t ws_size,
                              hipStream_t stream) {
    const float* c   = (const float*)d_in[0];
    const float* W1  = (const float*)d_in[1];
    const float* b1  = (const float*)d_in[2];
    const float* W2  = (const float*)d_in[3];
    const float* b2  = (const float*)d_in[4];
    const float* cb  = (const float*)d_in[5];
    const float* Wmu = (const float*)d_in[6];
    const float* bmu = (const float*)d_in[7];
    const float* Wlv = (const float*)d_in[8];
    const float* blv = (const float*)d_in[9];
    float* out = (float*)d_out;
    unsigned char* ws = (unsigned char*)d_ws;
    float* partials = (float*)(ws + WS_PART);

    prep_kernel<<<(PN_TOT + 255) / 256, 256, 0, stream>>>(
        W1, b1, W2, b2, cb, Wmu, bmu, Wlv, blv, ws);
    fused_main<<<BN / 128, 256, 0, stream>>>(c, cb, ws, out, partials);
    loss_reduce<<<1, 256, 0, stream>>>(partials, out + 4 * (size_t)BN * DZ);
}